// Round 1
// baseline (2507.922 us; speedup 1.0000x reference)
//
#include <hip/hip_runtime.h>
#include <hip/hip_bf16.h>

#define BATCH 8192
#define DIN   4096
#define H1    128
#define NLAT  512
#define LAT   32

typedef short bf16x8 __attribute__((ext_vector_type(8)));
typedef float f32x4  __attribute__((ext_vector_type(4)));

static __device__ __forceinline__ unsigned short f2bf(float f) {
  union { float f; unsigned u; } v; v.f = f;
  return (unsigned short)((v.u + 0x7FFFu + ((v.u >> 16) & 1u)) >> 16);  // RNE
}

// ---- prep: W1 [4096][128] f32 -> W1T [128][4096] bf16 ----
__global__ void prep_w1t(const float* __restrict__ W1, unsigned short* __restrict__ W1T) {
  __shared__ float t[32][33];
  int k0 = blockIdx.x * 32;
  int n0 = blockIdx.y * 32;
  int tx = threadIdx.x & 31, ty = threadIdx.x >> 5;
#pragma unroll
  for (int i = 0; i < 32; i += 8)
    t[ty + i][tx] = W1[(size_t)(k0 + ty + i) * H1 + (n0 + tx)];
  __syncthreads();
#pragma unroll
  for (int i = 0; i < 32; i += 8)
    W1T[(size_t)(n0 + ty + i) * DIN + (k0 + tx)] = f2bf(t[tx][ty + i]);
}

// ---- prep: decoders flat [4096][32] f32 -> decT [32][4096] f32 ----
__global__ void prep_dect(const float* __restrict__ dec, float* __restrict__ decT) {
  __shared__ float t[32][33];
  int d0 = blockIdx.x * 32;
  int tx = threadIdx.x & 31, ty = threadIdx.x >> 5;
#pragma unroll
  for (int i = 0; i < 32; i += 8)
    t[ty + i][tx] = dec[(size_t)(d0 + ty + i) * LAT + tx];
  __syncthreads();
#pragma unroll
  for (int i = 0; i < 32; i += 8)
    decT[(size_t)(ty + i) * DIN + (d0 + tx)] = t[tx][ty + i];
}

// ---- gemm1: partial[si][8192][128] = x[:, ksl] @ W1[ksl, :] (bf16 MFMA) ----
// Each wave: 16 rows x 128 cols, one K-slice. No LDS: A from HBM (f32->bf16
// in-reg), B from L2-resident W1T with contiguous 16B fragment loads.
// A/B fragments use the SAME per-lane k ordering (k = (lane>>4)*8 + j), which
// is correct for any canonical HW k-layout as long as it's consistent A<->B.
__global__ __launch_bounds__(256, 4) void gemm1_kernel(
    const float* __restrict__ x, const unsigned short* __restrict__ W1T,
    float* __restrict__ partial, int kslices) {
  int w = (blockIdx.x << 2) + (threadIdx.x >> 6);
  int lane = threadIdx.x & 63;
  int rg = w & 511, si = w >> 9;
  int klen = DIN / kslices;
  int k0 = si * klen;
  int rbase = rg << 4;
  int kg = (lane >> 4) << 3;
  const float* xp = x + (size_t)(rbase + (lane & 15)) * DIN + k0 + kg;
  const unsigned short* bp = W1T + (size_t)(lane & 15) * DIN + k0 + kg;
  f32x4 acc[8];
#pragma unroll
  for (int i = 0; i < 8; i++) acc[i] = (f32x4){0.f, 0.f, 0.f, 0.f};
  for (int kk = 0; kk < klen; kk += 32) {
    f32x4 a0 = *(const f32x4*)(xp + kk);
    f32x4 a1 = *(const f32x4*)(xp + kk + 4);
    union { bf16x8 v; unsigned short u[8]; } af;
#pragma unroll
    for (int j = 0; j < 4; j++) { af.u[j] = f2bf(a0[j]); af.u[4 + j] = f2bf(a1[j]); }
#pragma unroll
    for (int nn = 0; nn < 8; nn++) {
      bf16x8 bv = *(const bf16x8*)(bp + (size_t)nn * 16 * DIN + kk);
      acc[nn] = __builtin_amdgcn_mfma_f32_16x16x32_bf16(af.v, bv, acc[nn], 0, 0, 0);
    }
  }
  // C/D layout (verified): col = lane&15, row = (lane>>4)*4 + j
  float* pb = partial + ((size_t)si * BATCH + rbase) * H1;
  int crow = (lane >> 4) << 2, ccol = lane & 15;
#pragma unroll
  for (int nn = 0; nn < 8; nn++)
#pragma unroll
    for (int j = 0; j < 4; j++)
      pb[(size_t)(crow + j) * H1 + nn * 16 + ccol] = acc[nn][j];
}

// ---- fused tail: h = relu(sum partials + b1); z = h@W2+b2 (out);
//      z_sum fold; recon = z_sum @ decT (out). 16 rows / block. ----
__global__ __launch_bounds__(256, 2) void tail_kernel(
    const float* __restrict__ partial, int kslices,
    const float* __restrict__ b1, const float* __restrict__ W2,
    const float* __restrict__ b2, const float* __restrict__ decT,
    float* __restrict__ zout, float* __restrict__ rout) {
  __shared__ float hs[16][128];
  __shared__ float zsp[16][32][4];
  __shared__ float zsum[16][32];
  int t = threadIdx.x;
  int rbase = blockIdx.x << 4;

  // phase 1: consolidate partials -> h in LDS
#pragma unroll
  for (int i = 0; i < 8; i++) {
    int idx = t + (i << 8);
    int r = idx >> 7, c = idx & 127;
    float s = b1[c];
    for (int si = 0; si < kslices; si++)
      s += partial[((size_t)si * BATCH + rbase + r) * H1 + c];
    hs[r][c] = fmaxf(s, 0.f);
  }
  __syncthreads();

  // phase 2: z. wave wq covers cols [wq*128, wq*128+128); lane -> c0, c0+64
  int wq = t >> 6, lane = t & 63;
  int c0 = (wq << 7) + lane;
  float acc0[16], acc1[16];
#pragma unroll
  for (int r = 0; r < 16; r++) { acc0[r] = 0.f; acc1[r] = 0.f; }
  for (int k4 = 0; k4 < 32; k4++) {
    float w2a[4], w2b[4];
#pragma unroll
    for (int j = 0; j < 4; j++) {
      w2a[j] = W2[(size_t)(k4 * 4 + j) * NLAT + c0];
      w2b[j] = W2[(size_t)(k4 * 4 + j) * NLAT + c0 + 64];
    }
#pragma unroll
    for (int rg = 0; rg < 4; rg++) {
      f32x4 hv[4];
#pragma unroll
      for (int rr = 0; rr < 4; rr++)
        hv[rr] = *(const f32x4*)&hs[rg * 4 + rr][k4 * 4];
#pragma unroll
      for (int rr = 0; rr < 4; rr++)
#pragma unroll
        for (int j = 0; j < 4; j++) {
          acc0[rg * 4 + rr] += hv[rr][j] * w2a[j];
          acc1[rg * 4 + rr] += hv[rr][j] * w2b[j];
        }
    }
  }
  float bb0 = b2[c0], bb1 = b2[c0 + 64];
#pragma unroll
  for (int r = 0; r < 16; r++) {
    float v0 = acc0[r] + bb0, v1 = acc1[r] + bb1;
    zout[(size_t)(rbase + r) * NLAT + c0] = v0;
    zout[(size_t)(rbase + r) * NLAT + c0 + 64] = v1;
    // z_sum fold: this thread's 2 cols share l = lane&31; lane^32 holds the
    // complementary factor set within this wave's 4 factors.
    float ps = v0 + v1;
    ps += __shfl_xor(ps, 32);
    if (lane < 32) zsp[r][lane][wq] = ps;
  }
  __syncthreads();
  // consolidate 4 wave-partials -> zsum (deterministic)
#pragma unroll
  for (int i = 0; i < 2; i++) {
    int idx = t + (i << 8);
    int r = idx >> 5, l = idx & 31;
    f32x4 p4 = *(const f32x4*)&zsp[r][l][0];
    zsum[r][l] = p4[0] + p4[1] + p4[2] + p4[3];
  }
  __syncthreads();

  // phase 3: recon. wave wq covers d-quarter [wq*1024, +1024), 256 cols/pass
  int dquart = wq << 10;
  for (int dt = 0; dt < 4; dt++) {
    int dcol = dquart + (dt << 8) + (lane << 2);
    f32x4 racc[16];
#pragma unroll
    for (int r = 0; r < 16; r++) racc[r] = (f32x4){0.f, 0.f, 0.f, 0.f};
#pragma unroll
    for (int l4 = 0; l4 < 8; l4++) {
      f32x4 dv[4];
#pragma unroll
      for (int j = 0; j < 4; j++)
        dv[j] = *(const f32x4*)(decT + (size_t)(l4 * 4 + j) * DIN + dcol);
#pragma unroll
      for (int rg = 0; rg < 4; rg++) {
        f32x4 zv[4];
#pragma unroll
        for (int rr = 0; rr < 4; rr++)
          zv[rr] = *(const f32x4*)&zsum[rg * 4 + rr][l4 * 4];
#pragma unroll
        for (int rr = 0; rr < 4; rr++)
#pragma unroll
          for (int j = 0; j < 4; j++)
            racc[rg * 4 + rr] += zv[rr][j] * dv[j];
      }
    }
#pragma unroll
    for (int r = 0; r < 16; r++)
      *(f32x4*)(rout + (size_t)(rbase + r) * DIN + dcol) = racc[r];
  }
}

extern "C" void kernel_launch(void* const* d_in, const int* in_sizes, int n_in,
                              void* d_out, int out_size, void* d_ws, size_t ws_size,
                              hipStream_t stream) {
  const float* x   = (const float*)d_in[0];
  const float* W1  = (const float*)d_in[1];
  const float* b1  = (const float*)d_in[2];
  const float* W2  = (const float*)d_in[3];
  const float* b2  = (const float*)d_in[4];
  const float* dec = (const float*)d_in[5];
  float* zout = (float*)d_out;
  float* rout = zout + (size_t)BATCH * NLAT;

  char* ws = (char*)d_ws;
  unsigned short* W1T = (unsigned short*)ws;                 // 1 MB
  float* decT = (float*)(ws + (1u << 20));                   // 512 KB
  float* partial = (float*)(ws + (1u << 20) + (512u << 10)); // ks * 4 MB
  const size_t fixed = (1u << 20) + (512u << 10);
  const size_t slice_bytes = (size_t)BATCH * H1 * 4;
  int ks = 1;
  if (ws_size >= fixed + 8 * slice_bytes)      ks = 8;
  else if (ws_size >= fixed + 4 * slice_bytes) ks = 4;
  else if (ws_size >= fixed + 2 * slice_bytes) ks = 2;

  prep_w1t<<<dim3(128, 4), 256, 0, stream>>>(W1, W1T);
  prep_dect<<<dim3(128), 256, 0, stream>>>(dec, decT);
  gemm1_kernel<<<dim3(128 * ks), 256, 0, stream>>>(x, W1T, partial, ks);
  tail_kernel<<<dim3(512), 256, 0, stream>>>(partial, ks, b1, W2, b2, decT, zout, rout);
}

// Round 2
// 169.904 us; speedup vs baseline: 14.7608x; 14.7608x over previous
//
#include <hip/hip_runtime.h>
#include <hip/hip_bf16.h>

#define BATCH 8192
#define DIN   4096
#define H1    128
#define NLAT  512
#define LAT   32

typedef short bf16x8 __attribute__((ext_vector_type(8)));
typedef float f32x4  __attribute__((ext_vector_type(4)));

static __device__ __forceinline__ unsigned short f2bf(float f) {
  union { float f; unsigned u; } v; v.f = f;
  return (unsigned short)((v.u + 0x7FFFu + ((v.u >> 16) & 1u)) >> 16);  // RNE
}

// ---- prep: W1 [4096][128] f32 -> W1T [128][4096] bf16 ----
__global__ void prep_w1t(const float* __restrict__ W1, unsigned short* __restrict__ W1T) {
  __shared__ float t[32][33];
  int k0 = blockIdx.x * 32;
  int n0 = blockIdx.y * 32;
  int tx = threadIdx.x & 31, ty = threadIdx.x >> 5;
#pragma unroll
  for (int i = 0; i < 32; i += 8)
    t[ty + i][tx] = W1[(size_t)(k0 + ty + i) * H1 + (n0 + tx)];
  __syncthreads();
#pragma unroll
  for (int i = 0; i < 32; i += 8)
    W1T[(size_t)(n0 + ty + i) * DIN + (k0 + tx)] = f2bf(t[tx][ty + i]);
}

// ---- prep: decoders flat [4096][32] f32 -> decT [32][4096] f32 ----
__global__ void prep_dect(const float* __restrict__ dec, float* __restrict__ decT) {
  __shared__ float t[32][33];
  int d0 = blockIdx.x * 32;
  int tx = threadIdx.x & 31, ty = threadIdx.x >> 5;
#pragma unroll
  for (int i = 0; i < 32; i += 8)
    t[ty + i][tx] = dec[(size_t)(d0 + ty + i) * LAT + tx];
  __syncthreads();
#pragma unroll
  for (int i = 0; i < 32; i += 8)
    decT[(size_t)(ty + i) * DIN + (d0 + tx)] = t[tx][ty + i];
}

// ---- gemm1: partial[si][8192][128] = x[:, ksl] @ W1[ksl, :] (bf16 MFMA) ----
__global__ __launch_bounds__(256, 4) void gemm1_kernel(
    const float* __restrict__ x, const unsigned short* __restrict__ W1T,
    float* __restrict__ partial, int kslices) {
  int w = (blockIdx.x << 2) + (threadIdx.x >> 6);
  int lane = threadIdx.x & 63;
  int rg = w & 511, si = w >> 9;
  int klen = DIN / kslices;
  int k0 = si * klen;
  int rbase = rg << 4;
  int kg = (lane >> 4) << 3;
  const float* xp = x + (size_t)(rbase + (lane & 15)) * DIN + k0 + kg;
  const unsigned short* bp = W1T + (size_t)(lane & 15) * DIN + k0 + kg;
  f32x4 acc[8];
#pragma unroll
  for (int i = 0; i < 8; i++) acc[i] = (f32x4){0.f, 0.f, 0.f, 0.f};
  for (int kk = 0; kk < klen; kk += 32) {
    f32x4 a0 = *(const f32x4*)(xp + kk);
    f32x4 a1 = *(const f32x4*)(xp + kk + 4);
    union { bf16x8 v; unsigned short u[8]; } af;
#pragma unroll
    for (int j = 0; j < 4; j++) { af.u[j] = f2bf(a0[j]); af.u[4 + j] = f2bf(a1[j]); }
#pragma unroll
    for (int nn = 0; nn < 8; nn++) {
      bf16x8 bv = *(const bf16x8*)(bp + (size_t)nn * 16 * DIN + kk);
      acc[nn] = __builtin_amdgcn_mfma_f32_16x16x32_bf16(af.v, bv, acc[nn], 0, 0, 0);
    }
  }
  float* pb = partial + ((size_t)si * BATCH + rbase) * H1;
  int crow = (lane >> 4) << 2, ccol = lane & 15;
#pragma unroll
  for (int nn = 0; nn < 8; nn++)
#pragma unroll
    for (int j = 0; j < 4; j++)
      pb[(size_t)(crow + j) * H1 + nn * 16 + ccol] = acc[nn][j];
}

// ---- z_kernel: h = relu(sum partials + b1); z = h@W2+b2 -> zout;
//      zsum fold -> zsumg [BATCH][32]. 16 rows / block, ~60 VGPRs. ----
__global__ __launch_bounds__(256) void z_kernel(
    const float* __restrict__ partial, int kslices,
    const float* __restrict__ b1, const float* __restrict__ W2,
    const float* __restrict__ b2,
    float* __restrict__ zout, float* __restrict__ zsumg) {
  __shared__ float hs[16][128];
  __shared__ float zsp[16][32][4];
  int t = threadIdx.x;
  int rbase = blockIdx.x << 4;

  // phase 1: consolidate partials -> h in LDS
#pragma unroll
  for (int i = 0; i < 8; i++) {
    int idx = t + (i << 8);
    int r = idx >> 7, c = idx & 127;
    float s = b1[c];
    for (int si = 0; si < kslices; si++)
      s += partial[((size_t)si * BATCH + rbase + r) * H1 + c];
    hs[r][c] = fmaxf(s, 0.f);
  }
  __syncthreads();

  // phase 2: z. wave wq covers cols [wq*128, +128); lane -> c0, c0+64
  int wq = t >> 6, lane = t & 63;
  int c0 = (wq << 7) + lane;
  float acc0[16], acc1[16];
#pragma unroll
  for (int r = 0; r < 16; r++) { acc0[r] = 0.f; acc1[r] = 0.f; }
  for (int k4 = 0; k4 < 32; k4++) {
    float w2a[4], w2b[4];
#pragma unroll
    for (int j = 0; j < 4; j++) {
      w2a[j] = W2[(size_t)(k4 * 4 + j) * NLAT + c0];
      w2b[j] = W2[(size_t)(k4 * 4 + j) * NLAT + c0 + 64];
    }
#pragma unroll
    for (int rg = 0; rg < 4; rg++) {
      f32x4 hv[4];
#pragma unroll
      for (int rr = 0; rr < 4; rr++)
        hv[rr] = *(const f32x4*)&hs[rg * 4 + rr][k4 * 4];
#pragma unroll
      for (int rr = 0; rr < 4; rr++)
#pragma unroll
        for (int j = 0; j < 4; j++) {
          acc0[rg * 4 + rr] += hv[rr][j] * w2a[j];
          acc1[rg * 4 + rr] += hv[rr][j] * w2b[j];
        }
    }
  }
  float bb0 = b2[c0], bb1 = b2[c0 + 64];
#pragma unroll
  for (int r = 0; r < 16; r++) {
    float v0 = acc0[r] + bb0, v1 = acc1[r] + bb1;
    zout[(size_t)(rbase + r) * NLAT + c0] = v0;
    zout[(size_t)(rbase + r) * NLAT + c0 + 64] = v1;
    float ps = v0 + v1;               // two factors, same latent index
    ps += __shfl_xor(ps, 32);         // + complementary factor pair
    if (lane < 32) zsp[r][lane][wq] = ps;
  }
  __syncthreads();
  // consolidate 4 wave-partials -> zsum global (deterministic order)
#pragma unroll
  for (int i = 0; i < 2; i++) {
    int idx = t + (i << 8);
    int r = idx >> 5, l = idx & 31;
    f32x4 p4 = *(const f32x4*)&zsp[r][l][0];
    zsumg[(size_t)(rbase + r) * LAT + l] = p4[0] + p4[1] + p4[2] + p4[3];
  }
}

// ---- recon_kernel: rout[b][d] = sum_l zsum[b][l] * decT[l][d].
//      Block: 32 rows x 256 cols; wave: 8 rows; thread: 8 rows x 4 cols.
//      acc[8] f32x4 = 32 VGPRs; zsum broadcast from LDS; decT from L2. ----
__global__ __launch_bounds__(256) void recon_kernel(
    const float* __restrict__ zsumg, const float* __restrict__ decT,
    float* __restrict__ rout) {
  __shared__ float zs[32][32];
  int t = threadIdx.x;
  int rbase = (blockIdx.x >> 4) << 5;
  int dcol0 = (blockIdx.x & 15) << 8;
  {
    int r = t >> 3, c4 = (t & 7) << 2;
    *(f32x4*)&zs[r][c4] = *(const f32x4*)(zsumg + (size_t)(rbase + r) * LAT + c4);
  }
  __syncthreads();
  int wq = t >> 6, lane = t & 63;
  int r0 = wq << 3;
  int dcol = dcol0 + (lane << 2);
  f32x4 acc[8];
#pragma unroll
  for (int r = 0; r < 8; r++) acc[r] = (f32x4){0.f, 0.f, 0.f, 0.f};
#pragma unroll 8
  for (int l = 0; l < 32; l++) {
    f32x4 dv = *(const f32x4*)(decT + (size_t)l * DIN + dcol);
#pragma unroll
    for (int r = 0; r < 8; r++) {
      float zv = zs[r0 + r][l];
#pragma unroll
      for (int j = 0; j < 4; j++) acc[r][j] += zv * dv[j];
    }
  }
#pragma unroll
  for (int r = 0; r < 8; r++)
    *(f32x4*)(rout + (size_t)(rbase + r0 + r) * DIN + dcol) = acc[r];
}

extern "C" void kernel_launch(void* const* d_in, const int* in_sizes, int n_in,
                              void* d_out, int out_size, void* d_ws, size_t ws_size,
                              hipStream_t stream) {
  const float* x   = (const float*)d_in[0];
  const float* W1  = (const float*)d_in[1];
  const float* b1  = (const float*)d_in[2];
  const float* W2  = (const float*)d_in[3];
  const float* b2  = (const float*)d_in[4];
  const float* dec = (const float*)d_in[5];
  float* zout = (float*)d_out;
  float* rout = zout + (size_t)BATCH * NLAT;

  char* ws = (char*)d_ws;
  unsigned short* W1T = (unsigned short*)ws;                     // 1 MB
  float* decT  = (float*)(ws + (1u << 20));                      // 512 KB
  float* zsumg = (float*)(ws + (1u << 20) + (512u << 10));       // 1 MB
  float* partial = (float*)(ws + (2u << 20) + (512u << 10));     // ks * 4 MB
  const size_t fixed = (2u << 20) + (512u << 10);
  const size_t slice_bytes = (size_t)BATCH * H1 * 4;
  int ks = 1;
  if (ws_size >= fixed + 8 * slice_bytes)      ks = 8;
  else if (ws_size >= fixed + 4 * slice_bytes) ks = 4;
  else if (ws_size >= fixed + 2 * slice_bytes) ks = 2;

  prep_w1t<<<dim3(128, 4), 256, 0, stream>>>(W1, W1T);
  prep_dect<<<dim3(128), 256, 0, stream>>>(dec, decT);
  gemm1_kernel<<<dim3(128 * ks), 256, 0, stream>>>(x, W1T, partial, ks);
  z_kernel<<<dim3(512), 256, 0, stream>>>(partial, ks, b1, W2, b2, zout, zsumg);
  recon_kernel<<<dim3(4096), 256, 0, stream>>>(zsumg, decT, rout);
}